// Round 13
// baseline (189.145 us; speedup 1.0000x reference)
//
#include <hip/hip_runtime.h>
#include <hip/hip_bf16.h>
#include <cstdint>

// LSTM cell: g[g,b,n] = sum_k A[b,k] * Wcat[g,k,n],  A = [x | h]  (K = 2048)
// i,f,o = sigmoid(g0,1,2), u = tanh(g3), c_t = i*u + f*c, h_t = o*tanh(c_t)
// Round 13: occupancy experiment — 3 blocks/CU (12 waves/CU, 3/SIMD; every
// prior round ran 2/SIMD). 16x16x32 MFMA (acc 64 AGPR), BM=128, BN=32/gate,
// BK=32, 3 x 16KB LDS bufs, one barrier + counted VMW(4) per K-step.
// Prep: fused single-dispatch pass (r12, verified).

#define LDS_TOTAL 49152     // 3 bufs x (A 8KB + B 8KB)

typedef __attribute__((ext_vector_type(8))) short bf16x8;    // 8 bf16 = 4 VGPR
typedef __attribute__((ext_vector_type(4))) float f32x4;     // 16x16 acc
typedef __attribute__((ext_vector_type(4))) unsigned int u32x4;

static __device__ __forceinline__ unsigned short f2bf(float f) {
  union { float f; unsigned int u; } v; v.f = f;
  unsigned int u = v.u;
  unsigned int r = (u + 0x7FFFu + ((u >> 16) & 1u)) >> 16;  // RTN-even
  return (unsigned short)r;
}

static __device__ __forceinline__ void load16(const void* gp, void* lp) {
  __builtin_amdgcn_global_load_lds(
      (const __attribute__((address_space(1))) void*)gp,
      (__attribute__((address_space(3))) void*)lp, 16, 0, 0);
}

static __device__ __forceinline__ float sigmoid_f(float x) {
  return 1.0f / (1.0f + __expf(-x));
}
static __device__ __forceinline__ float tanh_f(float x) {
  float e = __expf(-2.0f * fabsf(x));
  float r = (1.0f - e) / (1.0f + e);
  return copysignf(r, x);
}

// ---- fused prep: blocks 0..4095 pack A; blocks 4096..6143 transpose W ----
// pack A:  Ap[kblk 256][b 8192][8]  (k-chunked bf16, 64x64 LDS transpose)
// prep W:  Wt2[kblk 256][g 4][n 1024][8]
__global__ __launch_bounds__(256) void prep_fused_kernel(
    const float* __restrict__ x, const float* __restrict__ h,
    const float* __restrict__ Wx, const float* __restrict__ Wh,
    unsigned short* __restrict__ Ap, unsigned short* __restrict__ Wt2) {
  __shared__ float tile[64][65];
  const int r = threadIdx.x >> 4;
  const int c4 = (threadIdx.x & 15) << 2;
  if (blockIdx.x < 4096) {                     // ---- pack A ----
    const int b0 = (blockIdx.x >> 5) << 6;
    const int k0 = (blockIdx.x & 31) << 6;
    const float* src; int ks;
    if (k0 < 1024) { src = x; ks = k0; } else { src = h; ks = k0 - 1024; }
    #pragma unroll
    for (int s = 0; s < 4; ++s) {
      float4 v = *(const float4*)(src + (size_t)(b0 + s * 16 + r) * 1024 + ks + c4);
      tile[s * 16 + r][c4 + 0] = v.x; tile[s * 16 + r][c4 + 1] = v.y;
      tile[s * 16 + r][c4 + 2] = v.z; tile[s * 16 + r][c4 + 3] = v.w;
    }
    __syncthreads();
    #pragma unroll
    for (int i = 0; i < 2; ++i) {
      int cc = i * 256 + threadIdx.x;
      int kb = cc >> 6, bb = cc & 63;
      union { unsigned short s[8]; u32x4 v; } o;
      #pragma unroll
      for (int e = 0; e < 8; ++e) o.s[e] = f2bf(tile[bb][kb * 8 + e]);
      *(u32x4*)(Ap + ((size_t)((k0 >> 3) + kb) * 8192 + b0 + bb) * 8) = o.v;
    }
  } else {                                     // ---- prep W ----
    const int bid = blockIdx.x - 4096;
    const int g = bid >> 9;
    const int kt = (bid >> 4) & 31;
    const int nt = bid & 15;
    const int k0 = kt << 6, n0 = nt << 6;
    const float* W; int ks;
    if (k0 < 1024) { W = Wx + (size_t)g * 1048576; ks = k0; }
    else           { W = Wh + (size_t)g * 1048576; ks = k0 - 1024; }
    #pragma unroll
    for (int s = 0; s < 4; ++s) {
      float4 v = *(const float4*)(W + (size_t)(ks + s * 16 + r) * 1024 + n0 + c4);
      tile[s * 16 + r][c4 + 0] = v.x; tile[s * 16 + r][c4 + 1] = v.y;
      tile[s * 16 + r][c4 + 2] = v.z; tile[s * 16 + r][c4 + 3] = v.w;
    }
    __syncthreads();
    #pragma unroll
    for (int i = 0; i < 2; ++i) {
      int cc = i * 256 + threadIdx.x;
      int kb = cc >> 6, nn = cc & 63;
      union { unsigned short s[8]; u32x4 v; } o;
      #pragma unroll
      for (int e = 0; e < 8; ++e) o.s[e] = f2bf(tile[kb * 8 + e][nn]);
      *(u32x4*)(Wt2 + ((size_t)((k0 >> 3) + kb) * 4096 + g * 1024 + n0 + nn) * 8) = o.v;
    }
  }
}

#define VMW(n) asm volatile("s_waitcnt vmcnt(" #n ")" ::: "memory")
#define LGKM0() asm volatile("s_waitcnt lgkmcnt(0)" ::: "memory")
#define BAR() __builtin_amdgcn_s_barrier()

// ---- main: fused 4-gate GEMM (16x16x32) + LSTM epilogue, 3 blocks/CU ----
// 256 thr = 4 waves: wr = w>>1 (rows wr*64..+64), wc = w&1 (n wc*16..+16/gate).
// LDS buf 16KB: A[4 kblk][128 row][16B] @0, B[4 kblk][4 g][32 n][16B] @8192.
// 64 K-steps (BK=32). Step: VMW(4) [drain stage(t), keep stage(t+1)]; BAR;
// stage(t+2 -> spare buf, 4 gloads); 8 ds_read_b128; LGKM0; 16 MFMA.
// One barrier/step: BAR(t) proves reads(t-1) retired (each wave's LGKM0
// precedes its arrival), so stage(t+2) into buf[(t-1)%3] is safe.
__global__ __launch_bounds__(256, 3) void lstm_gemm_kernel(
    const unsigned short* __restrict__ Ap,     // [256 kblk][8192 b][8]
    const unsigned short* __restrict__ Wt2,    // [256 kblk][4 g][1024 n][8]
    const float* __restrict__ cprev,
    float* __restrict__ out) {
  extern __shared__ char lds[];
  const int tid = threadIdx.x;
  const int l = tid & 63;
  const int w = tid >> 6;
  const int wr = w >> 1;               // 0..1
  const int wc = w & 1;                // 0..1
  const int bid = blockIdx.x;          // 2048 blocks
  const int xcd = bid & 7;             // nt-slab/XCD: W-slab 4x0.5MB L2-resident
  const int cc = bid >> 3;             // 0..255
  const int nt = xcd * 4 + (cc >> 6);  // 32 n-tiles
  const int mt = cc & 63;              // 64 m-tiles
  const int m0 = mt << 7;              // BM = 128
  const int n0 = nt << 5;              // 32 n / gate

  f32x4 acc[4][4];                     // [m-frag][gate] -> 64 AGPR
  #pragma unroll
  for (int mf = 0; mf < 4; ++mf)
    #pragma unroll
    for (int g = 0; g < 4; ++g) acc[mf][g] = (f32x4)0.0f;

  const int lr = l & 15;
  const int kb4 = l >> 4;              // kblk within step: k = kb4*8 + e

  // LDS read bases: every 16-lane group reads 256B contiguous (conflict-free)
  const int aBase = kb4 * 2048 + (wr * 64 + lr) * 16;          // +mf*256
  const int bBase = 8192 + kb4 * 2048 + (wc * 16 + lr) * 16;   // +g*512

  // Stage bases. A: chunk c=j*256+tid -> kblk=j*2+(tid>>7), row=tid&127.
  const unsigned short* const gA =
      Ap + (size_t)(tid >> 7) * 65536 + (size_t)(m0 + (tid & 127)) * 8;
  // B: kblk=j*2+(tid>>7), g=(tid>>5)&3, n=tid&31.
  const unsigned short* const gB =
      Wt2 + (size_t)(tid >> 7) * 32768 + (size_t)((tid >> 5) & 3) * 8192 +
      (size_t)(n0 + (tid & 31)) * 8;
  const int dA = (tid & ~63) << 4;     // wave-uniform base + lane*16 (HW rule)
  const int dB = 8192 + dA;

  auto stage = [&](int bo, int t) {    // 4 gloads: A 2 (1KB coalesced), B 2
    const unsigned short* a0 = gA + (size_t)t * 262144;   // 4 kblk x 65536
    load16(a0,          lds + bo + dA);
    load16(a0 + 131072, lds + bo + dA + 4096);            // +2 kblk
    const unsigned short* b0 = gB + (size_t)t * 131072;   // 4 kblk x 32768
    load16(b0,          lds + bo + dB);
    load16(b0 + 65536,  lds + bo + dB + 4096);            // +2 kblk
  };

  bf16x8 aR[4], bR[4];
  auto rd8 = [&](int bo) {             // 8 ds_read_b128, conflict-free
    const char* p = lds + bo;
    aR[0] = *(const bf16x8*)(p + aBase);
    aR[1] = *(const bf16x8*)(p + aBase + 256);    // +16 rows
    aR[2] = *(const bf16x8*)(p + aBase + 512);
    aR[3] = *(const bf16x8*)(p + aBase + 768);
    bR[0] = *(const bf16x8*)(p + bBase);
    bR[1] = *(const bf16x8*)(p + bBase + 512);    // +1 gate
    bR[2] = *(const bf16x8*)(p + bBase + 1024);
    bR[3] = *(const bf16x8*)(p + bBase + 1536);
  };

  // Prologue: stage t=0 -> buf0, t=1 -> buf1; loop's VMW(4) drains t=0.
  int bo0 = 0, bo1 = 16384, bo2 = 32768;  // cur / next / spare
  stage(bo0, 0);
  stage(bo1, 1);

  #pragma unroll 1
  for (int t = 0; t < 64; ++t) {
    if (t < 62) { VMW(4); } else { VMW(0); }
    BAR();
    if (t + 2 < 64) stage(bo2, t + 2);   // spare = buf of t-1, reads retired
    rd8(bo0);
    LGKM0();
    __builtin_amdgcn_s_setprio(1);
    #pragma unroll
    for (int mf = 0; mf < 4; ++mf)
      #pragma unroll
      for (int g = 0; g < 4; ++g)
        acc[mf][g] = __builtin_amdgcn_mfma_f32_16x16x32_bf16(
            aR[mf], bR[g], acc[mf][g], 0, 0, 0);
    __builtin_amdgcn_s_setprio(0);
    int tmp = bo0; bo0 = bo1; bo1 = bo2; bo2 = tmp;
  }

  // Epilogue: 16x16 C/D layout col = lane&15, row = (lane>>4)*4 + reg  [m89]
  const int q = (l >> 4) << 2;
  const int col = n0 + wc * 16 + lr;
  #pragma unroll
  for (int mf = 0; mf < 4; ++mf) {
    #pragma unroll
    for (int j = 0; j < 4; ++j) {
      int row = m0 + wr * 64 + mf * 16 + q + j;
      float gi = acc[mf][0][j];
      float gf = acc[mf][1][j];
      float go = acc[mf][2][j];
      float gu = acc[mf][3][j];
      float i_ = sigmoid_f(gi);
      float f_ = sigmoid_f(gf);
      float o_ = sigmoid_f(go);
      float u_ = tanh_f(gu);
      size_t idx = (size_t)row * 1024 + col;
      float ct = i_ * u_ + f_ * cprev[idx];
      float ht = o_ * tanh_f(ct);
      out[idx] = ht;                   // h_t
      out[8388608 + idx] = ct;         // c_t
    }
  }
}

extern "C" void kernel_launch(void* const* d_in, const int* in_sizes, int n_in,
                              void* d_out, int out_size, void* d_ws, size_t ws_size,
                              hipStream_t stream) {
  const float* x  = (const float*)d_in[0];
  const float* h  = (const float*)d_in[1];
  const float* c  = (const float*)d_in[2];
  const float* Wx = (const float*)d_in[3];
  const float* Wh = (const float*)d_in[4];
  float* out = (float*)d_out;

  unsigned short* Ap  = (unsigned short*)d_ws;                   // 33,554,432 B
  unsigned short* Wt2 = (unsigned short*)((char*)d_ws + 33554432); // 16,777,216 B

  prep_fused_kernel<<<6144, 256, 0, stream>>>(x, h, Wx, Wh, Ap, Wt2);
  lstm_gemm_kernel<<<dim3(2048), dim3(256), LDS_TOTAL, stream>>>(Ap, Wt2, c, out);
}